// Round 9
// baseline (897.867 us; speedup 1.0000x reference)
//
#include <hip/hip_runtime.h>
#include <hip/hip_bf16.h>
#include <math.h>

// Problem constants
#define BATCH 2
#define LSEQ 1024
#define DMODEL 1024
#define DINNER 2048
#define DSTATE 16
#define DTRANK 64
#define NROWS (BATCH * LSEQ)   // 2048 token rows
#define XROW 128               // padded x_proj width (96 -> 128)
#define NC 32                  // scan chunks
#define TCH (LSEQ / NC)        // 32 timesteps per chunk
#define NSPLIT 16              // x_proj split-K slices
#define NBLK 512               // 2 blocks/CU, co-resident via __launch_bounds__(256,2)
#define NTHR 256

typedef __bf16 bf16;
typedef __attribute__((ext_vector_type(8))) __bf16 bf16x8;
typedef __attribute__((ext_vector_type(2))) __bf16 bf16x2;
typedef __attribute__((ext_vector_type(4))) float floatx4;

struct MegaParams {
    const float *x0, *norm_w, *W_in, *conv_w, *conv_b, *W_x, *W_dt, *b_dt, *A, *Dp, *W_out;
    float *out;
    bf16 *xz, *h, *xc, *y, *WinT, *WxT, *WdtT, *WoutT, *dt, *delta;
    float *Pw, *BC, *Pbuf, *Sbuf;
    unsigned *bar;            // software grid-barrier counters (zeroed per launch)
};

// ---------------------------------------------------------------------------
// Software grid barrier (validated in R8 at 256 blocks; co-residency of all
// NBLK blocks guaranteed by __launch_bounds__(256,2) + 32KB LDS).
// ---------------------------------------------------------------------------
__device__ __forceinline__ void gridbar(unsigned* bar, int idx)
{
    __syncthreads();
    if (threadIdx.x == 0) {
        __threadfence();
        __hip_atomic_fetch_add(&bar[idx], 1u, __ATOMIC_ACQ_REL, __HIP_MEMORY_SCOPE_AGENT);
        while (__hip_atomic_load(&bar[idx], __ATOMIC_ACQUIRE, __HIP_MEMORY_SCOPE_AGENT) < NBLK)
            __builtin_amdgcn_s_sleep(2);
        __threadfence();
    }
    __syncthreads();
}

// ---------------------------------------------------------------------------
// bf16 MFMA GEMM stage (device function). TM/TN/BK templated.
// global_load_lds width-16 staging with XOR-swizzled K-chunks (free 2-way).
// MODE 0: C = acc                MODE 1: C = softplus(acc + bias[n])
// MODE 2: C = acc + resid[gm*ldr+gn]
// MODE 4: C[zslice*ldr + gm*ldc+gn] = acc   (split-K partials)
// ---------------------------------------------------------------------------
template<int MODE, bool BF16OUT, int TM_, int TN_, int BK_>
__device__ __forceinline__ void gemm_stage(
    bf16* smem,
    const bf16* __restrict__ A, int lda,
    const bf16* __restrict__ Bt, int ldb,
    void* __restrict__ Cv, int ldc,
    int Ksplit, long kbase, int zslice,
    const float* __restrict__ bias,
    const float* __restrict__ resid, int ldr,
    int bx, int by, int tid)
{
    constexpr int CA   = BK_ / 8;                  // chunks per row
    constexpr int ISSA = TM_ * BK_ * 2 / 4096;     // 4-KB staging issues for A
    constexpr int ISSB = TN_ * BK_ * 2 / 4096;
    constexpr int NA   = TM_ / 32;                 // A frags per wave
    constexpr int NB   = TN_ / 32;                 // B frags per wave
    constexpr int NH   = BK_ / 32;                 // K halves per iter

    bf16* As = smem;
    bf16* Bs = smem + TM_ * BK_;

    const int lane = tid & 63;
    const int wave = tid >> 6;
    const int l15  = lane & 15;
    const int quad = lane >> 4;
    const int wm   = (wave >> 1) * (TM_ / 2);
    const int wn   = (wave & 1) * (TN_ / 2);

    const int row0 = by * TM_;
    const int col0 = bx * TN_;

    const bf16* gA[ISSA]; bf16* lA[ISSA];
    const bf16* gB[ISSB]; bf16* lB[ISSB];
    #pragma unroll
    for (int i = 0; i < ISSA; ++i) {
        int c = i * 256 + wave * 64 + lane;
        int r = c / CA;
        int kc = (c % CA) ^ (r % CA);
        gA[i] = A + (size_t)(row0 + r) * lda + kbase + kc * 8;
        lA[i] = As + (size_t)(i * 256 + wave * 64) * 8;
    }
    #pragma unroll
    for (int i = 0; i < ISSB; ++i) {
        int c = i * 256 + wave * 64 + lane;
        int r = c / CA;
        int kc = (c % CA) ^ (r % CA);
        gB[i] = Bt + (size_t)(col0 + r) * ldb + kbase + kc * 8;
        lB[i] = Bs + (size_t)(i * 256 + wave * 64) * 8;
    }

    floatx4 acc[NA][NB];
    #pragma unroll
    for (int i = 0; i < NA; ++i)
        #pragma unroll
        for (int j = 0; j < NB; ++j)
            acc[i][j] = (floatx4){0.f, 0.f, 0.f, 0.f};

    const int kiters = Ksplit / BK_;
    for (int kk = 0; kk < kiters; ++kk) {
        __syncthreads();
        #pragma unroll
        for (int i = 0; i < ISSA; ++i) {
            __builtin_amdgcn_global_load_lds(
                (const __attribute__((address_space(1))) void*)gA[i],
                (__attribute__((address_space(3))) void*)lA[i], 16, 0, 0);
            gA[i] += BK_;
        }
        #pragma unroll
        for (int i = 0; i < ISSB; ++i) {
            __builtin_amdgcn_global_load_lds(
                (const __attribute__((address_space(1))) void*)gB[i],
                (__attribute__((address_space(3))) void*)lB[i], 16, 0, 0);
            gB[i] += BK_;
        }
        __syncthreads();

        #pragma unroll
        for (int h = 0; h < NH; ++h) {
            bf16x8 af[NA], bfr[NB];
            #pragma unroll
            for (int i = 0; i < NA; ++i) {
                int r = wm + i * 16 + l15;
                af[i] = *(const bf16x8*)&As[(size_t)r * BK_ +
                          (((h * 4 + quad) ^ (r % CA)) * 8)];
            }
            #pragma unroll
            for (int j = 0; j < NB; ++j) {
                int r = wn + j * 16 + l15;
                bfr[j] = *(const bf16x8*)&Bs[(size_t)r * BK_ +
                           (((h * 4 + quad) ^ (r % CA)) * 8)];
            }
            #pragma unroll
            for (int i = 0; i < NA; ++i)
                #pragma unroll
                for (int j = 0; j < NB; ++j)
                    acc[i][j] = __builtin_amdgcn_mfma_f32_16x16x32_bf16(
                                    af[i], bfr[j], acc[i][j], 0, 0, 0);
        }
    }

    // epilogue: D frag mapping col=lane&15, row=quad*4+reg
    #pragma unroll
    for (int i = 0; i < NA; ++i) {
        #pragma unroll
        for (int j = 0; j < NB; ++j) {
            const int gn = col0 + wn + j * 16 + l15;
            #pragma unroll
            for (int r = 0; r < 4; ++r) {
                const int gm = row0 + wm + i * 16 + quad * 4 + r;
                float v = acc[i][j][r];
                if (MODE == 1) {
                    v += bias[gn];
                    v = (v > 20.0f) ? v : log1pf(__expf(v));
                }
                if (MODE == 2) v += resid[(size_t)gm * ldr + gn];
                if (MODE == 4) {
                    ((float*)Cv)[(size_t)zslice * ldr + (size_t)gm * ldc + gn] = v;
                } else if (BF16OUT) {
                    ((bf16*)Cv)[(size_t)gm * ldc + gn] = (bf16)v;
                } else {
                    ((float*)Cv)[(size_t)gm * ldc + gn] = v;
                }
            }
        }
    }
}

// ---------------------------------------------------------------------------
// Chunked selective scan stage. unit u -> (chunk, dseg, b); 16 states/lane.
// P/S layout [b][k][n][DINNER] (coalesced). Phase2 fuses ymod epilogue.
// ---------------------------------------------------------------------------
template<bool FINAL>
__device__ __forceinline__ void scan_stage(
    float* smem, const MegaParams& P, int u, int tid)
{
    float (*sBC)[32] = (float(*)[32])smem;
    const int chunk = u & 31;
    const int dseg  = (u >> 5) & 7;
    const int b     = u >> 8;
    const int d     = dseg * 256 + tid;
    const int row0  = b * LSEQ + chunk * TCH;

    {
        int t = tid >> 3, c4 = (tid & 7) * 4;
        *(float4*)&sBC[t][c4] = *(const float4*)&P.BC[(size_t)(row0 + t) * 32 + c4];
    }

    float Ad[16];
    #pragma unroll
    for (int j = 0; j < 4; ++j) {
        float4 av = *(const float4*)&P.A[(size_t)d * DSTATE + j * 4];
        Ad[j*4+0] = av.x; Ad[j*4+1] = av.y; Ad[j*4+2] = av.z; Ad[j*4+3] = av.w;
    }

    const size_t psbase = ((size_t)(b * NC + chunk) * DSTATE) * DINNER + d;
    float S[16], Pr[16];
    if (FINAL) {
        #pragma unroll
        for (int n = 0; n < 16; ++n) S[n] = P.Sbuf[psbase + (size_t)n * DINNER];
    } else {
        #pragma unroll
        for (int n = 0; n < 16; ++n) { S[n] = 0.0f; Pr[n] = 1.0f; }
    }
    float Dpd = FINAL ? P.Dp[d] : 0.0f;

    __syncthreads();

    #pragma unroll 2
    for (int t = 0; t < TCH; ++t) {
        const size_t row = (size_t)(row0 + t);
        float dv = (float)P.delta[row * DINNER + d];
        float xv = (float)P.xc[row * DINNER + d];
        float uu = dv * xv;
        float yp[4] = {0.f, 0.f, 0.f, 0.f};
        #pragma unroll
        for (int n = 0; n < 16; ++n) {
            float dA = __expf(dv * Ad[n]);
            S[n] = dA * S[n] + uu * sBC[t][n];
            if (FINAL) {
                yp[n & 3] += S[n] * sBC[t][16 + n];
            } else {
                Pr[n] *= dA;
            }
        }
        if (FINAL) {
            float yv = (yp[0] + yp[1]) + (yp[2] + yp[3]);
            float res = (float)P.xz[row * (2 * DINNER) + DINNER + d];
            float sres = res / (1.0f + __expf(-res));
            P.y[row * DINNER + d] = (bf16)((yv + xv * Dpd) * sres);
        }
    }

    if (!FINAL) {
        #pragma unroll
        for (int n = 0; n < 16; ++n) {
            P.Pbuf[psbase + (size_t)n * DINNER] = Pr[n];
            P.Sbuf[psbase + (size_t)n * DINNER] = S[n];
        }
    }
    __syncthreads();
}

// ---------------------------------------------------------------------------
// Mega-kernel v2: 512 blocks (2/CU co-resident), every stage 512-parallel.
// ---------------------------------------------------------------------------
__global__ __launch_bounds__(256, 2) void mega_kernel(MegaParams P)
{
    __shared__ __attribute__((aligned(16))) char smem_raw[32768];
    bf16*  smem_bf = (bf16*)smem_raw;
    float* smem_f  = (float*)smem_raw;
    const int bid = blockIdx.x;
    const int tid = threadIdx.x;

    // ---- stage 1: prep (4 weight transposes + RMSNorm), grid-stride ----
    for (int u = bid; u < 8576; u += NBLK) {
        if (u < 6528) {
            const float* W; bf16* Wt; int K, N, Npad, bx, by;
            if (u < 4096)      { W = P.W_in;  Wt = P.WinT;  K = 1024; N = 4096; Npad = 4096; bx = u & 127; by = u >> 7; }
            else if (u < 4352) { int l = u - 4096; W = P.W_x;  Wt = P.WxT;  K = 2048; N = 96;   Npad = 128;  bx = l & 3;  by = l >> 2; }
            else if (u < 4480) { int l = u - 4352; W = P.W_dt; Wt = P.WdtT; K = 64;   N = 2048; Npad = 2048; bx = l & 63; by = l >> 6; }
            else               { int l = u - 4480; W = P.W_out;Wt = P.WoutT;K = 2048; N = 1024; Npad = 1024; bx = l & 31; by = l >> 5; }
            float (*tile)[33] = (float(*)[33])smem_f;
            const int n0 = bx * 32, k0 = by * 32;
            const int tx = tid & 31, ty = tid >> 5;
            #pragma unroll
            for (int i = 0; i < 32; i += 8) {
                int k = k0 + ty + i, n = n0 + tx;
                tile[ty + i][tx] = (k < K && n < N) ? W[(size_t)k * N + n] : 0.0f;
            }
            __syncthreads();
            #pragma unroll
            for (int i = 0; i < 32; i += 8) {
                int n = n0 + ty + i, k = k0 + tx;
                if (n < Npad && k < K)
                    Wt[(size_t)n * K + k] = (bf16)tile[tx][ty + i];
            }
        } else {
            const int row = u - 6528;
            const float* xr = P.x0 + (size_t)row * DMODEL;
            float4 v = *(const float4*)(xr + tid * 4);
            float ss = v.x * v.x + v.y * v.y + v.z * v.z + v.w * v.w;
            #pragma unroll
            for (int m = 32; m >= 1; m >>= 1) ss += __shfl_xor(ss, m);
            if ((tid & 63) == 0) smem_f[tid >> 6] = ss;
            __syncthreads();
            float total = smem_f[0] + smem_f[1] + smem_f[2] + smem_f[3];
            float scale = rsqrtf(total * (1.0f / DMODEL) + 1e-5f);
            float4 wv = *(const float4*)(P.norm_w + tid * 4);
            union { bf16 bb[4]; uint2 uu; } pk;
            pk.bb[0] = (bf16)(v.x * scale * wv.x);
            pk.bb[1] = (bf16)(v.y * scale * wv.y);
            pk.bb[2] = (bf16)(v.z * scale * wv.z);
            pk.bb[3] = (bf16)(v.w * scale * wv.w);
            *(uint2*)(P.h + (size_t)row * DMODEL + tid * 4) = pk.uu;
        }
        __syncthreads();   // LDS WAR across grid-stride iterations
    }
    gridbar(P.bar, 0);

    // ---- stage 2: xz = h @ W_in, 128x128 tiles, 16x32 = 512 blocks ----
    gemm_stage<0, true, 128, 128, 64>(smem_bf,
        P.h, DMODEL, P.WinT, DMODEL, P.xz, 2 * DINNER,
        DMODEL, 0, 0, nullptr, nullptr, 0, bid & 31, bid >> 5, tid);
    gridbar(P.bar, 1);

    // ---- stage 3: causal conv(K=4)+SiLU, 2 ch/thread, grid-stride ----
    for (int idx = bid * NTHR + tid; idx < NROWS * DINNER / 2; idx += NBLK * NTHR) {
        int c2 = (idx & (DINNER / 2 - 1)) * 2;
        int row = idx >> 10;
        int l = row & (LSEQ - 1);
        float4 wA = *(const float4*)&P.conv_w[c2 * 4];
        float4 wB = *(const float4*)&P.conv_w[c2 * 4 + 4];
        float2 bb = *(const float2*)&P.conv_b[c2];
        const bf16* xr = P.xz + (size_t)row * (2 * DINNER) + c2;
        bf16x2 p0 = *(const bf16x2*)xr;
        float a0 = bb.x + (float)p0[0] * wA.w;
        float a1 = bb.y + (float)p0[1] * wB.w;
        if (l >= 1) { bf16x2 pq = *(const bf16x2*)(xr - 2 * DINNER); a0 += (float)pq[0] * wA.z; a1 += (float)pq[1] * wB.z; }
        if (l >= 2) { bf16x2 pq = *(const bf16x2*)(xr - 4 * DINNER); a0 += (float)pq[0] * wA.y; a1 += (float)pq[1] * wB.y; }
        if (l >= 3) { bf16x2 pq = *(const bf16x2*)(xr - 6 * DINNER); a0 += (float)pq[0] * wA.x; a1 += (float)pq[1] * wB.x; }
        a0 = a0 / (1.0f + __expf(-a0));
        a1 = a1 / (1.0f + __expf(-a1));
        bf16x2 o; o[0] = (bf16)a0; o[1] = (bf16)a1;
        *(bf16x2*)(P.xc + (size_t)row * DINNER + c2) = o;
    }
    gridbar(P.bar, 2);

    // ---- stage 4: x_proj split-K=16 partials (256 active blocks) ----
    if (bid < 16 * NSPLIT) {
        int by = bid & 15, bz = bid >> 4;
        gemm_stage<4, false, 128, 128, 64>(smem_bf,
            P.xc, DINNER, P.WxT, DINNER, P.Pw, XROW,
            DINNER / NSPLIT, (long)bz * (DINNER / NSPLIT), bz,
            nullptr, nullptr, NROWS * XROW, 0, by, tid);
    }
    gridbar(P.bar, 3);

    // ---- stage 5: reduce 16 slices -> dt_bf + BC ----
    for (int idx = bid * NTHR + tid; idx < NROWS * XROW; idx += NBLK * NTHR) {
        int row = idx >> 7, c = idx & 127;
        float s = 0.0f;
        #pragma unroll
        for (int k = 0; k < NSPLIT; ++k)
            s += P.Pw[(size_t)k * NROWS * XROW + idx];
        if (c < 64) P.dt[(size_t)row * 64 + c] = (bf16)s;
        else if (c < 96) P.BC[(size_t)row * 32 + (c - 64)] = s;
    }
    gridbar(P.bar, 4);

    // ---- stage 6: delta = softplus(dt @ W_dt + b_dt), TM=64/TN=128, 16x32=512 ----
    gemm_stage<1, true, 64, 128, 64>(smem_bf,
        P.dt, DTRANK, P.WdtT, DTRANK, P.delta, DINNER,
        DTRANK, 0, 0, P.b_dt, nullptr, 0, bid & 15, bid >> 4, tid);
    gridbar(P.bar, 5);

    // ---- stage 7: scan phase 1, 512 units, 1 per block ----
    scan_stage<false>(smem_f, P, bid, tid);
    gridbar(P.bar, 6);

    // ---- stage 8: chunk combine (65536 lanes; half the threads) ----
    {
        int gid = bid * NTHR + tid;
        if (gid < BATCH * DSTATE * DINNER) {
            int b = gid >> 15;
            int nd = gid & 32767;
            float carry = 0.0f;
            for (int k = 0; k < NC; ++k) {
                size_t off = ((size_t)(b * NC + k) << 15) + nd;
                float pk = P.Pbuf[off];
                float sk = P.Sbuf[off];
                P.Sbuf[off] = carry;
                carry = pk * carry + sk;
            }
        }
    }
    gridbar(P.bar, 7);

    // ---- stage 9: scan phase 2 (+ fused ymod) -> y_bf ----
    scan_stage<true>(smem_f, P, bid, tid);
    gridbar(P.bar, 8);

    // ---- stage 10: out = x0 + y @ W_out, TM=64/TN=64, 16x32=512 blocks ----
    gemm_stage<2, false, 64, 64, 64>(smem_bf,
        P.y, DINNER, P.WoutT, DINNER, P.out, DMODEL,
        DINNER, 0, 0, nullptr, P.x0, DMODEL, bid & 15, bid >> 4, tid);
}

// ---------------------------------------------------------------------------
extern "C" void kernel_launch(void* const* d_in, const int* in_sizes, int n_in,
                              void* d_out, int out_size, void* d_ws, size_t ws_size,
                              hipStream_t stream)
{
    MegaParams prm;
    prm.x0     = (const float*)d_in[0];
    prm.norm_w = (const float*)d_in[1];
    prm.W_in   = (const float*)d_in[2];
    prm.conv_w = (const float*)d_in[3];
    prm.conv_b = (const float*)d_in[4];
    prm.W_x    = (const float*)d_in[5];
    prm.W_dt   = (const float*)d_in[6];
    prm.b_dt   = (const float*)d_in[7];
    prm.A      = (const float*)d_in[8];
    prm.Dp     = (const float*)d_in[9];
    prm.W_out  = (const float*)d_in[10];
    prm.out    = (float*)d_out;

    char* p = (char*)d_ws;
    prm.bar   = (unsigned*)p; p += 256;                                 // barrier counters
    prm.xz    = (bf16*)p;   p += (size_t)NROWS * 2 * DINNER * 2;        // 16MB
    prm.Pw    = (float*)p;  p += (size_t)NSPLIT * NROWS * XROW * 4;     // 16MB
    prm.BC    = (float*)p;  p += (size_t)NROWS * 32 * 4;                // 0.25MB
    prm.delta = (bf16*)p;   p += (size_t)NROWS * DINNER * 2;            // 8MB
    prm.Pbuf  = (float*)p;  p += (size_t)BATCH * NC * DINNER * 16 * 4;  // 8MB
    prm.Sbuf  = (float*)p;  p += (size_t)BATCH * NC * DINNER * 16 * 4;  // 8MB
    prm.h     = (bf16*)p;   p += (size_t)NROWS * DMODEL * 2;            // 4MB
    prm.xc    = (bf16*)p;   p += (size_t)NROWS * DINNER * 2;            // 8MB
    prm.y     = (bf16*)p;   p += (size_t)NROWS * DINNER * 2;            // 8MB
    prm.WinT  = (bf16*)p;   p += (size_t)(2 * DINNER) * DMODEL * 2;     // 8MB
    prm.WxT   = (bf16*)p;   p += (size_t)XROW * DINNER * 2;             // 0.5MB
    prm.WdtT  = (bf16*)p;   p += (size_t)DINNER * DTRANK * 2;           // 0.25MB
    prm.WoutT = (bf16*)p;   p += (size_t)DMODEL * DINNER * 2;           // 4MB
    prm.dt    = (bf16*)p;   p += (size_t)NROWS * DTRANK * 2;            // 0.25MB

    // zero the barrier counters (graph-capturable async memset)
    hipMemsetAsync(prm.bar, 0, 256, stream);

    mega_kernel<<<dim3(NBLK), dim3(NTHR), 0, stream>>>(prm);
}

// Round 11
// 449.972 us; speedup vs baseline: 1.9954x; 1.9954x over previous
//
#include <hip/hip_runtime.h>
#include <hip/hip_bf16.h>
#include <math.h>

// Problem constants
#define BATCH 2
#define LSEQ 1024
#define DMODEL 1024
#define DINNER 2048
#define DSTATE 16
#define DTRANK 64
#define NROWS (BATCH * LSEQ)   // 2048 token rows
#define XROW 128               // padded x_proj width (96 -> 128)
#define NC 32                  // scan chunks
#define TCH (LSEQ / NC)        // 32 timesteps per chunk
#define NSPLIT 16              // x_proj split-K slices
#define MBLK 256               // mid-kernel grid: 256 blocks = R8-proven barrier config
#define NTHR 256

typedef __bf16 bf16;
typedef __attribute__((ext_vector_type(8))) __bf16 bf16x8;
typedef __attribute__((ext_vector_type(2))) __bf16 bf16x2;
typedef __attribute__((ext_vector_type(4))) float floatx4;

struct MidParams {
    const float *conv_w, *conv_b, *b_dt, *A, *Dp;
    const bf16 *xz, *WxT, *WdtT;
    bf16 *xc, *y, *dt, *delta;
    float *Pw, *BC, *Pbuf, *Sbuf;
    unsigned *bar;
};

// ---------------------------------------------------------------------------
// Software grid barrier — ONLY used at 256 blocks (R8-validated: any VGPR
// count <= hw max keeps all 256 blocks resident on 256 CUs; deadlock-free).
// ---------------------------------------------------------------------------
__device__ __forceinline__ void gridbar(unsigned* bar, int idx)
{
    __syncthreads();
    if (threadIdx.x == 0) {
        __threadfence();
        __hip_atomic_fetch_add(&bar[idx], 1u, __ATOMIC_ACQ_REL, __HIP_MEMORY_SCOPE_AGENT);
        while (__hip_atomic_load(&bar[idx], __ATOMIC_ACQUIRE, __HIP_MEMORY_SCOPE_AGENT) < MBLK)
            __builtin_amdgcn_s_sleep(2);
        __threadfence();
    }
    __syncthreads();
}

// ---------------------------------------------------------------------------
// bf16 MFMA GEMM core (device). TM/TN/BK templated.
// global_load_lds width-16 staging with XOR-swizzled K-chunks (free 2-way).
// MODE 0: C = acc                MODE 1: C = softplus(acc + bias[n])
// MODE 2: C = acc + resid[gm*ldr+gn]
// MODE 4: C[zslice*ldr + gm*ldc+gn] = acc   (split-K partials)
// ---------------------------------------------------------------------------
template<int MODE, bool BF16OUT, int TM_, int TN_, int BK_>
__device__ __forceinline__ void gemm_core(
    bf16* smem,
    const bf16* __restrict__ A, int lda,
    const bf16* __restrict__ Bt, int ldb,
    void* __restrict__ Cv, int ldc,
    int Ksplit, long kbase, int zslice,
    const float* __restrict__ bias,
    const float* __restrict__ resid, int ldr,
    int bx, int by, int tid)
{
    constexpr int CA   = BK_ / 8;
    constexpr int ISSA = TM_ * BK_ * 2 / 4096;
    constexpr int ISSB = TN_ * BK_ * 2 / 4096;
    constexpr int NA   = TM_ / 32;
    constexpr int NB   = TN_ / 32;
    constexpr int NH   = BK_ / 32;

    bf16* As = smem;
    bf16* Bs = smem + TM_ * BK_;

    const int lane = tid & 63;
    const int wave = tid >> 6;
    const int l15  = lane & 15;
    const int quad = lane >> 4;
    const int wm   = (wave >> 1) * (TM_ / 2);
    const int wn   = (wave & 1) * (TN_ / 2);

    const int row0 = by * TM_;
    const int col0 = bx * TN_;

    const bf16* gA[ISSA]; bf16* lA[ISSA];
    const bf16* gB[ISSB]; bf16* lB[ISSB];
    #pragma unroll
    for (int i = 0; i < ISSA; ++i) {
        int c = i * 256 + wave * 64 + lane;
        int r = c / CA;
        int kc = (c % CA) ^ (r % CA);
        gA[i] = A + (size_t)(row0 + r) * lda + kbase + kc * 8;
        lA[i] = As + (size_t)(i * 256 + wave * 64) * 8;
    }
    #pragma unroll
    for (int i = 0; i < ISSB; ++i) {
        int c = i * 256 + wave * 64 + lane;
        int r = c / CA;
        int kc = (c % CA) ^ (r % CA);
        gB[i] = Bt + (size_t)(col0 + r) * ldb + kbase + kc * 8;
        lB[i] = Bs + (size_t)(i * 256 + wave * 64) * 8;
    }

    floatx4 acc[NA][NB];
    #pragma unroll
    for (int i = 0; i < NA; ++i)
        #pragma unroll
        for (int j = 0; j < NB; ++j)
            acc[i][j] = (floatx4){0.f, 0.f, 0.f, 0.f};

    const int kiters = Ksplit / BK_;
    for (int kk = 0; kk < kiters; ++kk) {
        __syncthreads();
        #pragma unroll
        for (int i = 0; i < ISSA; ++i) {
            __builtin_amdgcn_global_load_lds(
                (const __attribute__((address_space(1))) void*)gA[i],
                (__attribute__((address_space(3))) void*)lA[i], 16, 0, 0);
            gA[i] += BK_;
        }
        #pragma unroll
        for (int i = 0; i < ISSB; ++i) {
            __builtin_amdgcn_global_load_lds(
                (const __attribute__((address_space(1))) void*)gB[i],
                (__attribute__((address_space(3))) void*)lB[i], 16, 0, 0);
            gB[i] += BK_;
        }
        __syncthreads();

        #pragma unroll
        for (int h = 0; h < NH; ++h) {
            bf16x8 af[NA], bfr[NB];
            #pragma unroll
            for (int i = 0; i < NA; ++i) {
                int r = wm + i * 16 + l15;
                af[i] = *(const bf16x8*)&As[(size_t)r * BK_ +
                          (((h * 4 + quad) ^ (r % CA)) * 8)];
            }
            #pragma unroll
            for (int j = 0; j < NB; ++j) {
                int r = wn + j * 16 + l15;
                bfr[j] = *(const bf16x8*)&Bs[(size_t)r * BK_ +
                           (((h * 4 + quad) ^ (r % CA)) * 8)];
            }
            #pragma unroll
            for (int i = 0; i < NA; ++i)
                #pragma unroll
                for (int j = 0; j < NB; ++j)
                    acc[i][j] = __builtin_amdgcn_mfma_f32_16x16x32_bf16(
                                    af[i], bfr[j], acc[i][j], 0, 0, 0);
        }
    }

    #pragma unroll
    for (int i = 0; i < NA; ++i) {
        #pragma unroll
        for (int j = 0; j < NB; ++j) {
            const int gn = col0 + wn + j * 16 + l15;
            #pragma unroll
            for (int r = 0; r < 4; ++r) {
                const int gm = row0 + wm + i * 16 + quad * 4 + r;
                float v = acc[i][j][r];
                if (MODE == 1) {
                    v += bias[gn];
                    v = (v > 20.0f) ? v : log1pf(__expf(v));
                }
                if (MODE == 2) v += resid[(size_t)gm * ldr + gn];
                if (MODE == 4) {
                    ((float*)Cv)[(size_t)zslice * ldr + (size_t)gm * ldc + gn] = v;
                } else if (BF16OUT) {
                    ((bf16*)Cv)[(size_t)gm * ldc + gn] = (bf16)v;
                } else {
                    ((float*)Cv)[(size_t)gm * ldc + gn] = v;
                }
            }
        }
    }
}

// Standalone GEMM kernel wrapper (for GEMM1 / GEMM4, free grid sizing).
template<int MODE, bool BF16OUT, int TM_, int TN_, int BK_>
__global__ __launch_bounds__(256) void gemm_kernel(
    const bf16* __restrict__ A, int lda,
    const bf16* __restrict__ Bt, int ldb,
    void* __restrict__ Cv, int ldc,
    int Ksplit,
    const float* __restrict__ bias,
    const float* __restrict__ resid, int ldr)
{
    __shared__ __attribute__((aligned(16))) bf16 smem[(TM_ + TN_) * BK_];
    gemm_core<MODE, BF16OUT, TM_, TN_, BK_>(smem, A, lda, Bt, ldb, Cv, ldc,
        Ksplit, 0, 0, bias, resid, ldr, blockIdx.x, blockIdx.y, threadIdx.x);
}

// ---------------------------------------------------------------------------
// Prep: 4 weight transposes (fp32->bf16 transposed, zero-pad) + RMSNorm.
// Grid = 8576 blocks (R5-proven).
// ---------------------------------------------------------------------------
__global__ __launch_bounds__(256) void prep_kernel(
    const float* __restrict__ W_in,  bf16* __restrict__ WinT,
    const float* __restrict__ W_x,   bf16* __restrict__ WxT,
    const float* __restrict__ W_dt,  bf16* __restrict__ WdtT,
    const float* __restrict__ W_out, bf16* __restrict__ WoutT,
    const float* __restrict__ x0, const float* __restrict__ norm_w,
    bf16* __restrict__ h)
{
    __shared__ float smem[32 * 33];
    const int bid = blockIdx.x;
    const int tid = threadIdx.x;

    if (bid < 6528) {
        const float* W; bf16* Wt; int K, N, Npad, bx, by;
        if (bid < 4096)      { W = W_in;  Wt = WinT;  K = 1024; N = 4096; Npad = 4096; bx = bid & 127; by = bid >> 7; }
        else if (bid < 4352) { int l = bid - 4096; W = W_x;  Wt = WxT;  K = 2048; N = 96;   Npad = 128;  bx = l & 3;  by = l >> 2; }
        else if (bid < 4480) { int l = bid - 4352; W = W_dt; Wt = WdtT; K = 64;   N = 2048; Npad = 2048; bx = l & 63; by = l >> 6; }
        else                 { int l = bid - 4480; W = W_out;Wt = WoutT;K = 2048; N = 1024; Npad = 1024; bx = l & 31; by = l >> 5; }
        float (*tile)[33] = (float(*)[33])smem;
        const int n0 = bx * 32, k0 = by * 32;
        const int tx = tid & 31, ty = tid >> 5;
        #pragma unroll
        for (int i = 0; i < 32; i += 8) {
            int k = k0 + ty + i, n = n0 + tx;
            tile[ty + i][tx] = (k < K && n < N) ? W[(size_t)k * N + n] : 0.0f;
        }
        __syncthreads();
        #pragma unroll
        for (int i = 0; i < 32; i += 8) {
            int n = n0 + ty + i, k = k0 + tx;
            if (n < Npad && k < K)
                Wt[(size_t)n * K + k] = (bf16)tile[tx][ty + i];
        }
    } else {
        const int row = bid - 6528;
        const float* xr = x0 + (size_t)row * DMODEL;
        float4 v = *(const float4*)(xr + tid * 4);
        float ss = v.x * v.x + v.y * v.y + v.z * v.z + v.w * v.w;
        #pragma unroll
        for (int m = 32; m >= 1; m >>= 1) ss += __shfl_xor(ss, m);
        if ((tid & 63) == 0) smem[tid >> 6] = ss;
        __syncthreads();
        float total = smem[0] + smem[1] + smem[2] + smem[3];
        float scale = rsqrtf(total * (1.0f / DMODEL) + 1e-5f);
        float4 wv = *(const float4*)(norm_w + tid * 4);
        union { bf16 bb[4]; uint2 uu; } pk;
        pk.bb[0] = (bf16)(v.x * scale * wv.x);
        pk.bb[1] = (bf16)(v.y * scale * wv.y);
        pk.bb[2] = (bf16)(v.z * scale * wv.z);
        pk.bb[3] = (bf16)(v.w * scale * wv.w);
        *(uint2*)(h + (size_t)row * DMODEL + tid * 4) = pk.uu;
    }
}

// ---------------------------------------------------------------------------
// Chunked selective scan stage (device). unit u -> (chunk, dseg, b).
// P/S layout [b][k][n][DINNER] (coalesced). Phase2 fuses ymod epilogue.
// ---------------------------------------------------------------------------
template<bool FINAL>
__device__ __forceinline__ void scan_stage(
    float* smem, const MidParams& P, int u, int tid)
{
    float (*sBC)[32] = (float(*)[32])smem;
    const int chunk = u & 31;
    const int dseg  = (u >> 5) & 7;
    const int b     = u >> 8;
    const int d     = dseg * 256 + tid;
    const int row0  = b * LSEQ + chunk * TCH;

    {
        int t = tid >> 3, c4 = (tid & 7) * 4;
        *(float4*)&sBC[t][c4] = *(const float4*)&P.BC[(size_t)(row0 + t) * 32 + c4];
    }

    float Ad[16];
    #pragma unroll
    for (int j = 0; j < 4; ++j) {
        float4 av = *(const float4*)&P.A[(size_t)d * DSTATE + j * 4];
        Ad[j*4+0] = av.x; Ad[j*4+1] = av.y; Ad[j*4+2] = av.z; Ad[j*4+3] = av.w;
    }

    const size_t psbase = ((size_t)(b * NC + chunk) * DSTATE) * DINNER + d;
    float S[16], Pr[16];
    if (FINAL) {
        #pragma unroll
        for (int n = 0; n < 16; ++n) S[n] = P.Sbuf[psbase + (size_t)n * DINNER];
    } else {
        #pragma unroll
        for (int n = 0; n < 16; ++n) { S[n] = 0.0f; Pr[n] = 1.0f; }
    }
    float Dpd = FINAL ? P.Dp[d] : 0.0f;

    __syncthreads();

    #pragma unroll 2
    for (int t = 0; t < TCH; ++t) {
        const size_t row = (size_t)(row0 + t);
        float dv = (float)P.delta[row * DINNER + d];
        float xv = (float)P.xc[row * DINNER + d];
        float uu = dv * xv;
        float yp[4] = {0.f, 0.f, 0.f, 0.f};
        #pragma unroll
        for (int n = 0; n < 16; ++n) {
            float dA = __expf(dv * Ad[n]);
            S[n] = dA * S[n] + uu * sBC[t][n];
            if (FINAL) {
                yp[n & 3] += S[n] * sBC[t][16 + n];
            } else {
                Pr[n] *= dA;
            }
        }
        if (FINAL) {
            float yv = (yp[0] + yp[1]) + (yp[2] + yp[3]);
            float res = (float)P.xz[row * (2 * DINNER) + DINNER + d];
            float sres = res / (1.0f + __expf(-res));
            P.y[row * DINNER + d] = (bf16)((yv + xv * Dpd) * sres);
        }
    }

    if (!FINAL) {
        #pragma unroll
        for (int n = 0; n < 16; ++n) {
            P.Pbuf[psbase + (size_t)n * DINNER] = Pr[n];
            P.Sbuf[psbase + (size_t)n * DINNER] = S[n];
        }
    }
    __syncthreads();
}

// ---------------------------------------------------------------------------
// Mid-kernel: conv -> x_proj(split-K) -> reduce -> delta-GEMM -> scan1 ->
// combine -> scan2.  256 blocks (R8-proven barrier config).
// ---------------------------------------------------------------------------
__global__ __launch_bounds__(256) void mid_kernel(MidParams P)
{
    __shared__ __attribute__((aligned(16))) char smem_raw[32768];
    bf16*  smem_bf = (bf16*)smem_raw;
    float* smem_f  = (float*)smem_raw;
    const int bid = blockIdx.x;
    const int tid = threadIdx.x;

    // ---- conv(K=4)+SiLU, 2 ch/thread, grid-stride ----
    for (int idx = bid * NTHR + tid; idx < NROWS * DINNER / 2; idx += MBLK * NTHR) {
        int c2 = (idx & (DINNER / 2 - 1)) * 2;
        int row = idx >> 10;
        int l = row & (LSEQ - 1);
        float4 wA = *(const float4*)&P.conv_w[c2 * 4];
        float4 wB = *(const float4*)&P.conv_w[c2 * 4 + 4];
        float2 bb = *(const float2*)&P.conv_b[c2];
        const bf16* xr = P.xz + (size_t)row * (2 * DINNER) + c2;
        bf16x2 p0 = *(const bf16x2*)xr;
        float a0 = bb.x + (float)p0[0] * wA.w;
        float a1 = bb.y + (float)p0[1] * wB.w;
        if (l >= 1) { bf16x2 pq = *(const bf16x2*)(xr - 2 * DINNER); a0 += (float)pq[0] * wA.z; a1 += (float)pq[1] * wB.z; }
        if (l >= 2) { bf16x2 pq = *(const bf16x2*)(xr - 4 * DINNER); a0 += (float)pq[0] * wA.y; a1 += (float)pq[1] * wB.y; }
        if (l >= 3) { bf16x2 pq = *(const bf16x2*)(xr - 6 * DINNER); a0 += (float)pq[0] * wA.x; a1 += (float)pq[1] * wB.x; }
        a0 = a0 / (1.0f + __expf(-a0));
        a1 = a1 / (1.0f + __expf(-a1));
        bf16x2 o; o[0] = (bf16)a0; o[1] = (bf16)a1;
        *(bf16x2*)(P.xc + (size_t)row * DINNER + c2) = o;
    }
    gridbar(P.bar, 0);

    // ---- x_proj split-K=16 partials: 16 row-tiles x 16 slices = 256 blocks ----
    {
        int by = bid & 15, bz = bid >> 4;
        gemm_core<4, false, 128, 128, 64>(smem_bf,
            P.xc, DINNER, P.WxT, DINNER, P.Pw, XROW,
            DINNER / NSPLIT, (long)bz * (DINNER / NSPLIT), bz,
            nullptr, nullptr, NROWS * XROW, 0, by, tid);
    }
    gridbar(P.bar, 1);

    // ---- reduce 16 slices -> dt_bf + BC ----
    for (int idx = bid * NTHR + tid; idx < NROWS * XROW; idx += MBLK * NTHR) {
        int row = idx >> 7, c = idx & 127;
        float s = 0.0f;
        #pragma unroll
        for (int k = 0; k < NSPLIT; ++k)
            s += P.Pw[(size_t)k * NROWS * XROW + idx];
        if (c < 64) P.dt[(size_t)row * 64 + c] = (bf16)s;
        else if (c < 96) P.BC[(size_t)row * 32 + (c - 64)] = s;
    }
    gridbar(P.bar, 2);

    // ---- delta = softplus(dt @ W_dt + b_dt), 128x128 tiles, 16x16 = 256 ----
    gemm_core<1, true, 128, 128, 64>(smem_bf,
        P.dt, DTRANK, P.WdtT, DTRANK, P.delta, DINNER,
        DTRANK, 0, 0, P.b_dt, nullptr, 0, bid & 15, bid >> 4, tid);
    gridbar(P.bar, 3);

    // ---- scan phase 1: 512 units, 2 per block ----
    for (int u = bid; u < 512; u += MBLK)
        scan_stage<false>(smem_f, P, u, tid);
    gridbar(P.bar, 4);

    // ---- chunk combine: exactly 256*256 = 65536 lanes ----
    {
        int gid = bid * NTHR + tid;
        int b = gid >> 15;
        int nd = gid & 32767;
        float carry = 0.0f;
        for (int k = 0; k < NC; ++k) {
            size_t off = ((size_t)(b * NC + k) << 15) + nd;
            float pk = P.Pbuf[off];
            float sk = P.Sbuf[off];
            P.Sbuf[off] = carry;
            carry = pk * carry + sk;
        }
    }
    gridbar(P.bar, 5);

    // ---- scan phase 2 (+ fused ymod) -> y_bf ----
    for (int u = bid; u < 512; u += MBLK)
        scan_stage<true>(smem_f, P, u, tid);
}

// ---------------------------------------------------------------------------
extern "C" void kernel_launch(void* const* d_in, const int* in_sizes, int n_in,
                              void* d_out, int out_size, void* d_ws, size_t ws_size,
                              hipStream_t stream)
{
    const float* x0     = (const float*)d_in[0];
    const float* norm_w = (const float*)d_in[1];
    const float* W_in   = (const float*)d_in[2];
    const float* conv_w = (const float*)d_in[3];
    const float* conv_b = (const float*)d_in[4];
    const float* W_x    = (const float*)d_in[5];
    const float* W_dt   = (const float*)d_in[6];
    const float* b_dt   = (const float*)d_in[7];
    const float* A      = (const float*)d_in[8];
    const float* Dp     = (const float*)d_in[9];
    const float* W_out  = (const float*)d_in[10];
    float* out = (float*)d_out;

    char* p = (char*)d_ws;
    unsigned* bar = (unsigned*)p; p += 256;                              // barrier counters
    bf16*  xz    = (bf16*)p;   p += (size_t)NROWS * 2 * DINNER * 2;      // 16MB
    float* Pw    = (float*)p;  p += (size_t)NSPLIT * NROWS * XROW * 4;   // 16MB
    float* BC    = (float*)p;  p += (size_t)NROWS * 32 * 4;              // 0.25MB
    bf16*  delta = (bf16*)p;   p += (size_t)NROWS * DINNER * 2;          // 8MB
    float* Pbuf  = (float*)p;  p += (size_t)BATCH * NC * DINNER * 16 * 4;// 8MB
    float* Sbuf  = (float*)p;  p += (size_t)BATCH * NC * DINNER * 16 * 4;// 8MB
    bf16*  h     = (bf16*)p;   p += (size_t)NROWS * DMODEL * 2;          // 4MB
    bf16*  xc    = (bf16*)p;   p += (size_t)NROWS * DINNER * 2;          // 8MB
    bf16*  y     = (bf16*)p;   p += (size_t)NROWS * DINNER * 2;          // 8MB
    bf16*  WinT  = (bf16*)p;   p += (size_t)(2 * DINNER) * DMODEL * 2;   // 8MB
    bf16*  WxT   = (bf16*)p;   p += (size_t)XROW * DINNER * 2;           // 0.5MB
    bf16*  WdtT  = (bf16*)p;   p += (size_t)DINNER * DTRANK * 2;         // 0.25MB
    bf16*  WoutT = (bf16*)p;   p += (size_t)DMODEL * DINNER * 2;         // 4MB
    bf16*  dt    = (bf16*)p;   p += (size_t)NROWS * DTRANK * 2;          // 0.25MB

    hipMemsetAsync(bar, 0, 256, stream);

    // 1. prep: weight transposes + RMSNorm
    prep_kernel<<<8576, 256, 0, stream>>>(W_in, WinT, W_x, WxT, W_dt, WdtT,
                                          W_out, WoutT, x0, norm_w, h);

    // 2. xz = h @ W_in  [2048,1024]x[1024,4096] -> bf16, 512 blocks, 2/CU
    gemm_kernel<0, true, 128, 128, 64><<<dim3(32, 16), 256, 0, stream>>>(
        h, DMODEL, WinT, DMODEL, xz, 2 * DINNER, DMODEL, nullptr, nullptr, 0);

    // 3. mid: conv -> x_proj -> reduce -> delta -> scan (256 blocks, sw barrier)
    MidParams mp;
    mp.conv_w = conv_w; mp.conv_b = conv_b; mp.b_dt = b_dt; mp.A = A; mp.Dp = Dp;
    mp.xz = xz; mp.WxT = WxT; mp.WdtT = WdtT;
    mp.xc = xc; mp.y = y; mp.dt = dt; mp.delta = delta;
    mp.Pw = Pw; mp.BC = BC; mp.Pbuf = Pbuf; mp.Sbuf = Sbuf; mp.bar = bar;
    mid_kernel<<<MBLK, NTHR, 0, stream>>>(mp);

    // 4. out = x0 + y @ W_out  [2048,2048]x[2048,1024], TM=64/TN=64, 512 blocks
    gemm_kernel<2, false, 64, 64, 64><<<dim3(16, 32), 256, 0, stream>>>(
        y, DINNER, WoutT, DINNER, out, DMODEL, DINNER, nullptr, x0, DMODEL);
}